// Round 1
// baseline (996.146 us; speedup 1.0000x reference)
//
#include <hip/hip_runtime.h>

// Masked mean-pool: out[b,d] = sum_s embed[b,s,d]*mask[b,s] / sum_s mask[b,s]
// mask[b,s] = token_ids[b,s] not in {0 (PAD), 101 (CLS), 102 (SEP)}
//
// B=512, S=512, D=768, fp32 in/out. Streaming-read bound: ~805 MB embed.

constexpr int B = 512;
constexpr int S = 512;
constexpr int D = 768;
constexpr int NV = D / 4;  // 192 float4 columns per (b,s) row; block = 192 threads (3 waves)

__global__ __launch_bounds__(NV) void masked_mean_kernel(
    const float4* __restrict__ embed,   // [B, S, NV] as float4
    const int* __restrict__ tok,        // [B, S]
    float4* __restrict__ out)           // [B, NV]
{
    const int b = blockIdx.x;
    const int t = threadIdx.x;

    __shared__ float maskf[S];

    // Stage mask for this batch row in LDS (coalesced int loads).
    for (int s = t; s < S; s += NV) {
        int id = tok[b * S + s];
        maskf[s] = (id != 0 && id != 101 && id != 102) ? 1.0f : 0.0f;
    }
    __syncthreads();

    // Each thread owns one float4 column; stream all S rows.
    // maskf[s] read is a same-address LDS broadcast (no bank conflicts), so
    // every thread can also redundantly accumulate the count -> no reduction.
    const float4* row = embed + (size_t)b * S * NV + t;
    float4 acc = make_float4(0.f, 0.f, 0.f, 0.f);
    float cnt = 0.f;

#pragma unroll 8
    for (int s = 0; s < S; ++s) {
        const float m = maskf[s];
        const float4 v = row[(size_t)s * NV];
        cnt += m;
        acc.x = fmaf(v.x, m, acc.x);
        acc.y = fmaf(v.y, m, acc.y);
        acc.z = fmaf(v.z, m, acc.z);
        acc.w = fmaf(v.w, m, acc.w);
    }

    const float inv = 1.0f / cnt;
    out[b * NV + t] = make_float4(acc.x * inv, acc.y * inv, acc.z * inv, acc.w * inv);
}

extern "C" void kernel_launch(void* const* d_in, const int* in_sizes, int n_in,
                              void* d_out, int out_size, void* d_ws, size_t ws_size,
                              hipStream_t stream) {
    const float4* embed = (const float4*)d_in[0];
    const int* tok = (const int*)d_in[1];
    float4* out = (float4*)d_out;

    masked_mean_kernel<<<dim3(B), dim3(NV), 0, stream>>>(embed, tok, out);
}